// Round 5
// baseline (367.446 us; speedup 1.0000x reference)
//
#include <hip/hip_runtime.h>
#include <stdint.h>

// ESN fused v7: LDS-traffic cut. 2-phase skeleton (v3), 4 waves, 2 barriers.
//   phase1: all waves GEMM(k) [l-split: wave owns 16 l-cols x 64 p] ; stagers load u(k+1)
//   phase2: wave0 scan(k)+direct global store ; waves1-2 stage uB(k+1) (b64)
// LDS cuts vs v3: B-frag reads 16->4 b128/wave; no pT writeback; no writeout reads;
// b64 staging; single-buffer uB+pT (34.8 KB).
// B=32, D_IN=64, D_STATE=1024, L=2048, LEAK=0.5
#define B_   32
#define H_   64
#define P_   1024
#define L_   2048
#define TL   64
#define PB   64
#define NCH  (L_ / TL)
#define UST  68   // uB row stride in u32 (row = 272 B, 16B-aligned)
#define PST  68   // pT row stride in f32

#define TWO_LOG2E 2.88539008177792681472f

typedef __attribute__((ext_vector_type(8))) short short8;
typedef __attribute__((ext_vector_type(4))) float f32x4;
typedef __attribute__((ext_vector_type(4))) int   i32x4;

// lowers to v_exp_f32 (hardware exp2)
#define EXP2(x) __builtin_exp2f(x)

__device__ __forceinline__ short8 as_short8(i32x4 v) {
    union { i32x4 i; short8 s; } u; u.i = v; return u.s;
}

// f = hi(bf16, trunc) + lo(bf16, RNE of remainder); packed as hi | lo<<16
__device__ __forceinline__ unsigned pack_hilo(float f) {
    unsigned ub = __float_as_uint(f);
    float    fh = __uint_as_float(ub & 0xFFFF0000u);
    float    rm = f - fh;                       // exact
    unsigned r  = __float_as_uint(rm);
    r += 0x7FFFu + ((r >> 16) & 1u);            // RNE to bf16
    return (ub >> 16) | (r & 0xFFFF0000u);
}

__global__ __launch_bounds__(256, 2)
void esn_fused(const float* __restrict__ u, const float* __restrict__ w_in,
               const float* __restrict__ w_hh, const float* __restrict__ bias,
               float* __restrict__ out) {
    __shared__ unsigned uB[TL * UST];   // [l][h] packed hi/lo bf16   17.4 KB
    __shared__ float    pT[PB * PST];   // [p][l]                     17.4 KB

    const int t   = threadIdx.x;
    const int bid = blockIdx.x;
    const int s_  = bid >> 3;                       // XCD swizzle: same-b on one XCD
    const int b   = ((s_ >> 4) << 3) | (bid & 7);
    const int p0  = (s_ & 15) * PB;

    const int wv  = t >> 6;        // wave: GEMM l-strip = wv*16; wave0 also scans
    const int ln  = t & 63;
    const int n16 = ln & 15;       // MFMA m/n index
    const int q   = ln >> 4;       // MFMA quad (k-group)

    const float* ub_ = u + (size_t)b * (H_ * L_);

    // ---- A-fragments: ALL p-tiles in every wave (l-split GEMM) ----
    short8 a_hi[4][2], a_lo[4][2];
    #pragma unroll
    for (int pt = 0; pt < 4; ++pt) {
        const float* wrow = w_in + (size_t)(p0 + pt * 16 + n16) * H_;
        #pragma unroll
        for (int s = 0; s < 2; ++s) {
            float v[8];
            *(float4*)&v[0] = *(const float4*)(wrow + s * 32 + q * 8);
            *(float4*)&v[4] = *(const float4*)(wrow + s * 32 + q * 8 + 4);
            #pragma unroll
            for (int j = 0; j < 8; ++j) {
                unsigned ub = __float_as_uint(v[j]);
                a_hi[pt][s][j] = (short)(ub >> 16);
                float rm = v[j] - __uint_as_float(ub & 0xFFFF0000u);
                unsigned r = __float_as_uint(rm);
                r += 0x7FFFu + ((r >> 16) & 1u);
                a_lo[pt][s][j] = (short)(r >> 16);
            }
        }
    }

    // scan state (wave 0, one p per lane) — constants pre-scaled by 2*log2e
    float x = 0.0f, d2l = 0.0f, bs2l = 0.0f;
    if (t < 64) {
        d2l  = TWO_LOG2E * w_hh[(size_t)(p0 + ln) * (P_ + 1)];
        bs2l = TWO_LOG2E * bias[p0 + ln];
    }

    // stagers: waves 1-2 (128 threads). Thread owns rows h={2a,2a+1}, l-quarter c.
    const bool stg = (wv == 1) || (wv == 2);
    const int  m   = t - 64;           // 0..127 for stagers
    const int  a2  = (m >> 2) << 1;    // h0 = 2a (even)
    const int  c   = m & 3;            // l-quarter: l in [16c, 16c+16)

    float4 pf0[4], pf1[4];

    // ---- prologue: load + stage chunk 0 (b64 writes: h-pair per word-pair) ----
    if (stg) {
        const float* s0 = ub_ + (size_t)a2 * L_ + 16 * c;
        #pragma unroll
        for (int j = 0; j < 4; ++j) {
            pf0[j] = *(const float4*)(s0 + 4 * j);
            pf1[j] = *(const float4*)(s0 + L_ + 4 * j);
        }
        #pragma unroll
        for (int j = 0; j < 4; ++j) {
            float v0[4], v1[4];
            *(float4*)v0 = pf0[j]; *(float4*)v1 = pf1[j];
            #pragma unroll
            for (int i = 0; i < 4; ++i) {
                const int l = 16 * c + 4 * j + i;
                *(uint2*)&uB[l * UST + a2] =
                    make_uint2(pack_hilo(v0[i]), pack_hilo(v1[i]));
            }
        }
    }
    __syncthreads();

    for (int k = 0; k < NCH; ++k) {
        // ---- phase1: stagers load u(k+1) into regs (drains under GEMM) ----
        if (stg) {
            const int kn = (k + 1 < NCH) ? k + 1 : k;
            const float* s0 = ub_ + (size_t)a2 * L_ + (size_t)kn * TL + 16 * c;
            #pragma unroll
            for (int j = 0; j < 4; ++j) {
                pf0[j] = *(const float4*)(s0 + 4 * j);
                pf1[j] = *(const float4*)(s0 + L_ + 4 * j);
            }
        }

        // ---- phase1: GEMM(k). Wave's l-strip: lb = wv*16+n16. B-frags read ONCE,
        //      reused across 4 p-tiles (16->4 b128 reads per wave). ----
        {
            const int lb = wv * 16 + n16;
            short8 bh[2], bl[2];
            #pragma unroll
            for (int s = 0; s < 2; ++s) {
                const unsigned* bp = &uB[lb * UST + s * 32 + q * 8];
                i32x4 r0 = *(const i32x4*)bp;
                i32x4 r1 = *(const i32x4*)(bp + 4);
                i32x4 fh, fl;
                fh.x = __builtin_amdgcn_perm(r0.y, r0.x, 0x05040100u);
                fh.y = __builtin_amdgcn_perm(r0.w, r0.z, 0x05040100u);
                fh.z = __builtin_amdgcn_perm(r1.y, r1.x, 0x05040100u);
                fh.w = __builtin_amdgcn_perm(r1.w, r1.z, 0x05040100u);
                fl.x = __builtin_amdgcn_perm(r0.y, r0.x, 0x07060302u);
                fl.y = __builtin_amdgcn_perm(r0.w, r0.z, 0x07060302u);
                fl.z = __builtin_amdgcn_perm(r1.y, r1.x, 0x07060302u);
                fl.w = __builtin_amdgcn_perm(r1.w, r1.z, 0x07060302u);
                bh[s] = as_short8(fh);
                bl[s] = as_short8(fl);
            }
            #pragma unroll
            for (int pt = 0; pt < 4; ++pt) {
                f32x4 acc = {0.0f, 0.0f, 0.0f, 0.0f};
                #pragma unroll
                for (int s = 0; s < 2; ++s) {
                    acc = __builtin_amdgcn_mfma_f32_16x16x32_bf16(a_hi[pt][s], bh[s], acc, 0, 0, 0);
                    acc = __builtin_amdgcn_mfma_f32_16x16x32_bf16(a_hi[pt][s], bl[s], acc, 0, 0, 0);
                    acc = __builtin_amdgcn_mfma_f32_16x16x32_bf16(a_lo[pt][s], bh[s], acc, 0, 0, 0);
                }
                // C/D: col(l)=n16 -> lb, row(p)=pt*16+q*4+r -> b32 scatter (2-way, free)
                #pragma unroll
                for (int r = 0; r < 4; ++r)
                    pT[(pt * 16 + q * 4 + r) * PST + lb] = acc[r];
            }
        }
        __syncthreads();   // A: pT complete; uB(k) reads done

        if (t < 64) {
            // ---- phase2: scan 64 steps on own p-row, store DIRECT to global.
            //      xs[0..7] are 8 consecutive l -> two float4 stores per group. ----
            float* row = &pT[ln * PST];
            float* gout = out + ((size_t)b * P_ + p0 + ln) * L_ + (size_t)k * TL;
            float4 va = ((float4*)row)[0], vb = ((float4*)row)[1];
            #pragma unroll
            for (int g = 0; g < 8; ++g) {
                float4 na, nb;
                if (g < 7) { na = ((float4*)row)[2*g + 2]; nb = ((float4*)row)[2*g + 3]; }
                float v0[8] = {va.x, va.y, va.z, va.w, vb.x, vb.y, vb.z, vb.w};
                float xs[8];
                #pragma unroll
                for (int mm = 0; mm < 8; ++mm) {
                    const float sv = fmaf(TWO_LOG2E, v0[mm], bs2l);            // off-chain
                    const float e  = EXP2(fmaf(x, d2l, sv));                   // fma, exp
                    x = fmaf(0.5f, x, 0.5f) - __builtin_amdgcn_rcpf(e + 1.0f); // add,rcp,sub
                    xs[mm] = x;
                }
                *(float4*)(gout + 8 * g)     = make_float4(xs[0], xs[1], xs[2], xs[3]);
                *(float4*)(gout + 8 * g + 4) = make_float4(xs[4], xs[5], xs[6], xs[7]);
                va = na; vb = nb;
            }
        } else if (stg && (k + 1 < NCH)) {
            // ---- phase2: stage uB(k+1), b64 h-pair writes ----
            #pragma unroll
            for (int j = 0; j < 4; ++j) {
                float v0[4], v1[4];
                *(float4*)v0 = pf0[j]; *(float4*)v1 = pf1[j];
                #pragma unroll
                for (int i = 0; i < 4; ++i) {
                    const int l = 16 * c + 4 * j + i;
                    *(uint2*)&uB[l * UST + a2] =
                        make_uint2(pack_hilo(v0[i]), pack_hilo(v1[i]));
                }
            }
        }
        __syncthreads();   // B: scan reads done (pT free); uB(k+1) staged
    }
}

extern "C" void kernel_launch(void* const* d_in, const int* in_sizes, int n_in,
                              void* d_out, int out_size, void* d_ws, size_t ws_size,
                              hipStream_t stream) {
    const float* u    = (const float*)d_in[0];  // [B, H, L]
    const float* w_in = (const float*)d_in[1];  // [P, H]
    const float* w_hh = (const float*)d_in[2];  // [P, P] (diag used)
    const float* bias = (const float*)d_in[3];  // [P]
    float* out = (float*)d_out;                 // [B, P, L]

    dim3 grid(B_ * (P_ / PB));  // 512 blocks
    dim3 block(256);
    esn_fused<<<grid, block, 0, stream>>>(u, w_in, w_hh, bias, out);
}